// Round 4
// baseline (102426.611 us; speedup 1.0000x reference)
//
#include <hip/hip_runtime.h>

// AugmentedLstm: B=16, T=2048, D=H=512.
// 64 persistent WGs x 256 threads. h' exchanged as packed u64 agent-scope
// relaxed atomics {2 x f16, u32 step-tag}; consumers poll tags (R3 proven
// path, 7443us). Round 7: XCD-LOCAL RELAY, hang-proof. Theory: coherent
// polls bypass XCD L2 (R0 FETCH arithmetic) so all 8 WGs/XCD re-pull the
// same 32KB/round over the fabric = 8x amplification. Fix: per XCD, a
// rank-0 relay polls IC hex (R3 loop), re-stores the verified tagged image
// into an XCD-private mailbox with PLAIN stores (dirty in local L2), store-
// ack fence (vmcnt(0)), then bumps a monotonic per-XCD flag (plain store).
// Consumers spin on ONE 8B sc0 flag load/round (L2-local, ~200cy), then
// fetch 8x16B sc0 and verify embedded tags (ground truth). ALL new waits
// are bounded with fallback to the R3 hex poll -> cannot hang: worst case
// equals R3 + bounded overhead. ws_size checked; relay disabled if the
// workspace can't hold the mailbox. XCC id via numeric s_getreg encoding.
//
// Math: g = (x_t + h)@Wt[:, :5H] + 2b  (pi and ps share W)
//       pi5 = (x+h)@W5 - h@W5 + b5     (highway input)

#define NG 64
#define BLK 256
#define BB 16
#define TT 2048
#define DD 512
#define HHH 512
#define CC 8

// Workspace layout in u64 units.
#define MBOX_OFF 8192                  // [8 xcd][2][4096] mailbox
#define FLAG_OFF (MBOX_OFF + 8 * 8192) // [8 xcd] flags, 64B-strided
#define CNT_OFF (FLAG_OFF + 64)        // 8 u32 rank counters (in 8 u64)
#define WS_U64 (CNT_OFF + 8)

typedef _Float16 f16;
typedef _Float16 f16x4 __attribute__((ext_vector_type(4)));
typedef _Float16 f16x8 __attribute__((ext_vector_type(8)));
typedef float f32x4 __attribute__((ext_vector_type(4)));
typedef unsigned long long u64;
typedef unsigned int u32;
typedef u32 u32x2 __attribute__((ext_vector_type(2)));
typedef u32 u32x4 __attribute__((ext_vector_type(4)));

__device__ __forceinline__ float sigf(float v) {
  return 1.0f / (1.0f + __expf(-v));
}
__device__ __forceinline__ float tanhfast(float v) {
  return 2.0f / (1.0f + __expf(-2.0f * v)) - 1.0f;
}

__global__ __launch_bounds__(BLK, 1) void lstm_scan(
    const float* __restrict__ x, const int* __restrict__ lengths,
    const float* __restrict__ W, const float* __restrict__ bias,
    float* __restrict__ out, u64* __restrict__ hex, int relayOn) {
  __shared__ f16 u_sw[BB * DD];        // u = x+h, swizzled A-frag order
  __shared__ f16 h_sw[BB * DD];        // h alone (for h@W5)
  __shared__ float gbuf[4 * 16 * 17];  // per-tile MFMA results
  __shared__ float cbuf[BB * CC];      // cell state
  __shared__ int relinfo[2];           // {xcc, rank}

  const int tid = threadIdx.x;
  const int wg = blockIdx.x;
  const int wave = tid >> 6;
  const int lane = tid & 63;
  const int q = lane >> 4;
  const int n16 = lane & 15;

  // ---- XCD identity + relay election (runtime; robust to placement).
  // s_getreg imm = id(20) | offset(0)<<6 | (size-1=31)<<11 = 63508.
  if (tid == 0) {
    int xcc = 0, rank = 1;
    if (relayOn) {
      u32 xv_ = __builtin_amdgcn_s_getreg(63508) & 7u;
      u32* cnt = (u32*)(hex + CNT_OFF);
      u32 r = __hip_atomic_fetch_add(cnt + xv_, 1u, __ATOMIC_RELAXED,
                                     __HIP_MEMORY_SCOPE_AGENT);
      xcc = (int)xv_;
      rank = (int)r;
    }
    relinfo[0] = xcc;
    relinfo[1] = rank;
  }

  // ---- Weight B-fragments in registers (loaded once).
  // Tiles 0..2: A=u, 16 cols = gates {0,1},{2,3},{4,5} x 8 cols.
  // Tile  3   : A=h, cols 0..7 = gate-5 rows (h@W5), cols 8..15 zero.
  f16x8 bW[16];
  {
    int grow = 0;
    bool valid = true;
    if (wave < 3) {
      int gate = 2 * wave + (n16 >> 3);
      grow = gate * HHH + wg * CC + (n16 & 7);
    } else if (n16 < 8) {
      grow = 5 * HHH + wg * CC + n16;
    } else {
      valid = false;
    }
    const float* wr = W + (size_t)grow * DD;
#pragma unroll
    for (int kk = 0; kk < 16; ++kk) {
      f16x8 v;
      if (valid) {
        const float* p = wr + kk * 32 + q * 8;
#pragma unroll
        for (int j = 0; j < 8; ++j) v[j] = (f16)p[j];
      } else {
#pragma unroll
        for (int j = 0; j < 8; ++j) v[j] = (f16)0.0f;
      }
      bW[kk] = v;
    }
  }

  // ---- Staging indices. Thread's i-th chunk = cols k..k+3 of row m of the
  // flat [16][512] matrix. LDS granule (8 f16): logical (kk*64 + L),
  // physical (kk*64 + (L ^ kk)) — XOR swizzle keeps ds_write at the 4-way
  // floor and ds_read_b128 conflict-free.
  int soffv[8], pidx[8];
  size_t xcm[8];
#pragma unroll
  for (int i = 0; i < 8; ++i) {
    int e = (tid + i * BLK) * 4;
    int m = e >> 9;
    int k = e & 511;
    pidx[i] = m * 256 + (k >> 1);      // u64 pair index (k multiple of 4)
    xcm[i] = (size_t)m * TT * DD + k;  // x[b=m][t][k] base
    int kk = k >> 5, qq = (k >> 3) & 3, j0 = k & 7;
    int L = qq * 16 + m;
    soffv[i] = (kk * 64 + (L ^ kk)) * 8 + j0;
  }

  // ---- Epilogue constants (threads 0..127: b = tid>>3, n = tid&7).
  const int eb = tid >> 3;
  const int en = tid & 7;
  float bb0 = 0, bb1 = 0, bb2 = 0, bb3 = 0, bb4 = 0, bb5 = 0;
  int mylen = 0;
  if (tid < 128) {
    int gc = wg * CC + en;
    bb0 = bias[0 * HHH + gc];
    bb1 = bias[1 * HHH + gc];
    bb2 = bias[2 * HHH + gc];
    bb3 = bias[3 * HHH + gc];
    bb4 = bias[4 * HHH + gc];
    bb5 = bias[5 * HHH + gc];
    mylen = lengths[eb];
    cbuf[tid] = 0.0f;
  }

  // Prefetch x(t=0).
  f32x4 xv[8];
#pragma unroll
  for (int i = 0; i < 8; ++i) xv[i] = *(const f32x4*)(x + xcm[i]);

  __syncthreads();
  const int myxcc = relinfo[0];
  // mode: 0=direct (R3), 1=relay, 2=consumer.
  const int mode = !relayOn ? 0 : (relinfo[1] == 0 ? 1 : 2);
  u64* const rb_base = hex + MBOX_OFF + (size_t)myxcc * 8192;
  u64* const fl = hex + FLAG_OFF + (size_t)myxcc * 8;

  for (int t = 0; t < TT; ++t) {
    const u32 wtag = (u32)t;
    u32 lo0[8], lo1[8];  // low 32b (2 f16) of each u64 in the pair
    bool have = false;

    if (mode == 2) {
      // ---- Consumer: bounded spin on the XCD flag (one 8B sc0 load per
      // round, L2-local). Flag >= t means mailbox slot t&1 holds tag-t
      // data (relay fences data before flag).
      const u64 need = (u64)t;
      u64 fv = 0;
      int sp = 0;
      do {
        asm volatile(
            "global_load_dwordx2 %0, %1, off sc0\n\t"
            "s_waitcnt vmcnt(0)"
            : "=v"(fv)
            : "v"(fl)
            : "memory");
      } while (fv < need && ++sp < 512);
      if (fv >= need) {
        // Fetch 8x16B from mailbox, verify embedded tags (bounded).
        const u64* rbr = rb_base + (size_t)(t & 1) * 4096;
        const u64* q0 = rbr + pidx[0];
        const u64* q1 = rbr + pidx[1];
        const u64* q2 = rbr + pidx[2];
        const u64* q3 = rbr + pidx[3];
        const u64* q4 = rbr + pidx[4];
        const u64* q5 = rbr + pidx[5];
        const u64* q6 = rbr + pidx[6];
        const u64* q7 = rbr + pidx[7];
        for (int rt = 0; rt < 64 && !have; ++rt) {
          u32x4 c0, c1, c2, c3, c4, c5, c6, c7;
          asm volatile(
              "global_load_dwordx4 %0, %8, off sc0\n\t"
              "global_load_dwordx4 %1, %9, off sc0\n\t"
              "global_load_dwordx4 %2, %10, off sc0\n\t"
              "global_load_dwordx4 %3, %11, off sc0\n\t"
              "global_load_dwordx4 %4, %12, off sc0\n\t"
              "global_load_dwordx4 %5, %13, off sc0\n\t"
              "global_load_dwordx4 %6, %14, off sc0\n\t"
              "global_load_dwordx4 %7, %15, off sc0\n\t"
              "s_waitcnt vmcnt(0)"
              : "=v"(c0), "=v"(c1), "=v"(c2), "=v"(c3), "=v"(c4), "=v"(c5),
                "=v"(c6), "=v"(c7)
              : "v"(q0), "v"(q1), "v"(q2), "v"(q3), "v"(q4), "v"(q5),
                "v"(q6), "v"(q7)
              : "memory");
          u32 bad = (c0[1] ^ wtag) | (c0[3] ^ wtag);
          bad |= (c1[1] ^ wtag) | (c1[3] ^ wtag);
          bad |= (c2[1] ^ wtag) | (c2[3] ^ wtag);
          bad |= (c3[1] ^ wtag) | (c3[3] ^ wtag);
          bad |= (c4[1] ^ wtag) | (c4[3] ^ wtag);
          bad |= (c5[1] ^ wtag) | (c5[3] ^ wtag);
          bad |= (c6[1] ^ wtag) | (c6[3] ^ wtag);
          bad |= (c7[1] ^ wtag) | (c7[3] ^ wtag);
          if (bad == 0) {
            lo0[0] = c0[0]; lo1[0] = c0[2];
            lo0[1] = c1[0]; lo1[1] = c1[2];
            lo0[2] = c2[0]; lo1[2] = c2[2];
            lo0[3] = c3[0]; lo1[3] = c3[2];
            lo0[4] = c4[0]; lo1[4] = c4[2];
            lo0[5] = c5[0]; lo1[5] = c5[2];
            lo0[6] = c6[0]; lo1[6] = c6[2];
            lo0[7] = c7[0]; lo1[7] = c7[2];
            have = true;
          }
        }
      }
    }

    if (!have) {
      // ---- Direct IC hex poll (R3 proven; terminates by grid progress).
      // Relay always takes this; consumers only on bounded-spin timeout.
      const u64* hb = hex + (size_t)(t & 1) * 4096;
      u64 w0[8], w1[8];
      for (;;) {
#pragma unroll
        for (int i = 0; i < 8; ++i) {
          w0[i] = __hip_atomic_load(hb + pidx[i], __ATOMIC_RELAXED,
                                    __HIP_MEMORY_SCOPE_AGENT);
          w1[i] = __hip_atomic_load(hb + pidx[i] + 1, __ATOMIC_RELAXED,
                                    __HIP_MEMORY_SCOPE_AGENT);
        }
        unsigned bad = 0;
#pragma unroll
        for (int i = 0; i < 8; ++i)
          bad |= ((unsigned)(w0[i] >> 32) ^ wtag) |
                 ((unsigned)(w1[i] >> 32) ^ wtag);
        if (bad == 0) break;
      }
      if (mode == 1) {
        // Relay: re-publish verified image into the XCD mailbox (plain
        // stores -> dirty in local L2), fence store-acks, bump flag.
        u64* rbw = rb_base + (size_t)(t & 1) * 4096;
#pragma unroll
        for (int i = 0; i < 8; ++i) {
          __hip_atomic_store(rbw + pidx[i], w0[i], __ATOMIC_RELAXED,
                             __HIP_MEMORY_SCOPE_WORKGROUP);
          __hip_atomic_store(rbw + pidx[i] + 1, w1[i], __ATOMIC_RELAXED,
                             __HIP_MEMORY_SCOPE_WORKGROUP);
        }
        asm volatile("s_waitcnt vmcnt(0)" ::: "memory");
        if (tid == 0)
          __hip_atomic_store(fl, (u64)t, __ATOMIC_RELAXED,
                             __HIP_MEMORY_SCOPE_WORKGROUP);
      }
#pragma unroll
      for (int i = 0; i < 8; ++i) {
        lo0[i] = (u32)w0[i];
        lo1[i] = (u32)w1[i];
      }
    }

    // ---- Stage u = f16(x)+h and h into LDS (swizzled).
#pragma unroll
    for (int i = 0; i < 8; ++i) {
      u32x2 hp;
      hp[0] = lo0[i];
      hp[1] = lo1[i];
      f16x4 hv = __builtin_bit_cast(f16x4, hp);
      f16x4 uv;
#pragma unroll
      for (int j = 0; j < 4; ++j) uv[j] = (f16)xv[i][j] + hv[j];
      *(f16x4*)(u_sw + soffv[i]) = uv;
      *(f16x4*)(h_sw + soffv[i]) = hv;
    }
    __syncthreads();

    // ---- MFMA: wave's 16-col tile, K=512, 4 independent chains.
    f32x4 acc0 = {0.f, 0.f, 0.f, 0.f}, acc1 = {0.f, 0.f, 0.f, 0.f};
    f32x4 acc2 = {0.f, 0.f, 0.f, 0.f}, acc3 = {0.f, 0.f, 0.f, 0.f};
    const f16* asrc = (wave < 3) ? u_sw : h_sw;
#pragma unroll
    for (int kk = 0; kk < 16; kk += 4) {
      f16x8 a0 = *(const f16x8*)(asrc + (kk * 64 + (lane ^ kk)) * 8);
      f16x8 a1 =
          *(const f16x8*)(asrc + ((kk + 1) * 64 + (lane ^ (kk + 1))) * 8);
      f16x8 a2 =
          *(const f16x8*)(asrc + ((kk + 2) * 64 + (lane ^ (kk + 2))) * 8);
      f16x8 a3 =
          *(const f16x8*)(asrc + ((kk + 3) * 64 + (lane ^ (kk + 3))) * 8);
      acc0 = __builtin_amdgcn_mfma_f32_16x16x32_f16(a0, bW[kk], acc0, 0, 0, 0);
      acc1 =
          __builtin_amdgcn_mfma_f32_16x16x32_f16(a1, bW[kk + 1], acc1, 0, 0, 0);
      acc2 =
          __builtin_amdgcn_mfma_f32_16x16x32_f16(a2, bW[kk + 2], acc2, 0, 0, 0);
      acc3 =
          __builtin_amdgcn_mfma_f32_16x16x32_f16(a3, bW[kk + 3], acc3, 0, 0, 0);
    }
#pragma unroll
    for (int r = 0; r < 4; ++r)
      gbuf[wave * 272 + (q * 4 + r) * 17 + n16] =
          (acc0[r] + acc1[r]) + (acc2[r] + acc3[r]);
    __syncthreads();

    // ---- Epilogue (fp32) + direct publish (waves 0-1; partner via shfl).
    if (tid < 128) {
      float g0 = gbuf[0 * 272 + eb * 17 + en] + 2.f * bb0;      // i
      float g1 = gbuf[0 * 272 + eb * 17 + en + 8] + 2.f * bb1;  // f
      float g2 = gbuf[1 * 272 + eb * 17 + en] + 2.f * bb2;      // m~
      float g3 = gbuf[1 * 272 + eb * 17 + en + 8] + 2.f * bb3;  // o
      float g4 = gbuf[2 * 272 + eb * 17 + en] + 2.f * bb4;      // hw
      float p5 = gbuf[2 * 272 + eb * 17 + en + 8];              // (x+h)@W5
      float qv = gbuf[3 * 272 + eb * 17 + en];                  // h@W5
      float ig = sigf(g0), fg = sigf(g1), mt = tanhfast(g2);
      float og = sigf(g3), hwv = sigf(g4);
      float pi5 = p5 - qv + bb5;
      float cold = cbuf[tid];
      float mem = ig * mt + fg * cold;
      float o1 = og * tanhfast(mem);
      float ov = hwv * o1 + (1.0f - hwv) * pi5;
      float msk = (t < mylen) ? 1.0f : 0.0f;
      ov *= msk;
      mem *= msk;
      cbuf[tid] = mem;

      unsigned hbits =
          (unsigned)__builtin_bit_cast(unsigned short, (f16)ov);
      unsigned other = (unsigned)__shfl_xor((int)hbits, 1, 64);
      if ((en & 1) == 0) {
        u64 wv = (u64)(hbits & 0xffffu) | ((u64)(other & 0xffffu) << 16) |
                 ((u64)(unsigned)(t + 1) << 32);
        __hip_atomic_store(
            hex + (size_t)((t + 1) & 1) * 4096 + eb * 256 + wg * 4 + (en >> 1),
            wv, __ATOMIC_RELAXED, __HIP_MEMORY_SCOPE_AGENT);
      }
      // Out store after publish: keep the publish at the head of the
      // store queue.
      out[((size_t)eb * TT + t) * HHH + wg * CC + en] = ov;
    }

    // Prefetch x(t+1); latency hides under next step's polling.
    if (t + 1 < TT) {
#pragma unroll
      for (int i = 0; i < 8; ++i)
        xv[i] = *(const f32x4*)(x + xcm[i] + (size_t)(t + 1) * DD);
    }
    // No trailing __syncthreads: next-step staging only touches u_sw/h_sw,
    // whose step-t reads completed before the post-MFMA barrier; gbuf
    // writes for t+1 are fenced by the next post-staging barrier. Mailbox
    // slot reuse: relay rewrites parity p at t+2 only after all hex tags
    // == t+2, which requires every WG to have completed steps t and t+1,
    // i.e. consumed slot-p tag-t data. Flag monotonicity: flag <= t+1 when
    // any consumer is still at step t (its t+1 publish is pending), so a
    // passing flag always refers to intact slot data (tags re-verify it).
  }
}

extern "C" void kernel_launch(void* const* d_in, const int* in_sizes, int n_in,
                              void* d_out, int out_size, void* d_ws,
                              size_t ws_size, hipStream_t stream) {
  (void)in_sizes;
  (void)n_in;
  (void)out_size;
  const float* x = (const float*)d_in[0];
  const int* lengths = (const int*)d_in[1];
  const float* W = (const float*)d_in[2];
  const float* bias = (const float*)d_in[3];
  float* out = (float*)d_out;

  // hex [2][4096] u64 + mailbox [8][2][4096] + flags + rank counters.
  // Relay only if the workspace holds it all; else exact R3 behavior.
  u64* hex = (u64*)d_ws;
  int relayOn = (ws_size >= (size_t)WS_U64 * sizeof(u64)) ? 1 : 0;
  size_t clr = relayOn ? (size_t)WS_U64 * sizeof(u64)
                       : (size_t)2 * 4096 * sizeof(u64);
  hipMemsetAsync(d_ws, 0, clr, stream);

  lstm_scan<<<dim3(NG), dim3(BLK), 0, stream>>>(x, lengths, W, bias, out, hex,
                                                relayOn);
}

// Round 5
// 7042.368 us; speedup vs baseline: 14.5443x; 14.5443x over previous
//
#include <hip/hip_runtime.h>

// AugmentedLstm: B=16, T=2048, D=H=512.
// 64 persistent WGs x 256 threads. No grid barrier: h' published as packed
// u64 agent-scope relaxed atomics {2 x f16, u32 step-tag}; consumers poll
// tags (R3 proven structure, 7443us). Round 8: 8x REPLICATED PUBLISH.
// Unified theory from R3/R4/R5/R7: poll bursts (128 readers per IC line
// per round) queue ahead of the 2 publish stores on the same line, so
// store visibility inflates from ~400cy to thousands; late visibility =>
// more failed rounds => more reader pressure (convoy). Fix: publishers
// store each tagged u64 to 8 replicas of hex; consumer WG polls ONLY
// replica wg&7 -> readers/line drop 8x, writer commits fast, reads spread
// across 8x more IC banks. Poll loop / tags / parity / staging / MFMA /
// epilogue are byte-identical to R3 (single-variable experiment).
// Fallback nrep=1 == exact R3 if workspace is too small.
//
// Math: g = (x_t + h)@Wt[:, :5H] + 2b  (pi and ps share W)
//       pi5 = (x+h)@W5 - h@W5 + b5     (highway input)

#define NG 64
#define BLK 256
#define BB 16
#define TT 2048
#define DD 512
#define HHH 512
#define CC 8

typedef _Float16 f16;
typedef _Float16 f16x4 __attribute__((ext_vector_type(4)));
typedef _Float16 f16x8 __attribute__((ext_vector_type(8)));
typedef float f32x4 __attribute__((ext_vector_type(4)));
typedef unsigned long long u64;

__device__ __forceinline__ float sigf(float v) {
  return 1.0f / (1.0f + __expf(-v));
}
__device__ __forceinline__ float tanhfast(float v) {
  return 2.0f / (1.0f + __expf(-2.0f * v)) - 1.0f;
}

__device__ __forceinline__ f16 h_lo(u64 w) {
  return __builtin_bit_cast(f16, (unsigned short)(w & 0xffffu));
}
__device__ __forceinline__ f16 h_hi(u64 w) {
  return __builtin_bit_cast(f16, (unsigned short)((w >> 16) & 0xffffu));
}

__global__ __launch_bounds__(BLK, 1) void lstm_scan(
    const float* __restrict__ x, const int* __restrict__ lengths,
    const float* __restrict__ W, const float* __restrict__ bias,
    float* __restrict__ out,
    u64* __restrict__ hex /* [nrep][2][16][256] tagged */, int repmask) {
  __shared__ f16 u_sw[BB * DD];        // u = x+h, swizzled A-frag order
  __shared__ f16 h_sw[BB * DD];        // h alone (for h@W5)
  __shared__ float gbuf[4 * 16 * 17];  // per-tile MFMA results
  __shared__ float cbuf[BB * CC];      // cell state

  const int tid = threadIdx.x;
  const int wg = blockIdx.x;
  const int wave = tid >> 6;
  const int lane = tid & 63;
  const int q = lane >> 4;
  const int n16 = lane & 15;
  const int nrep = repmask + 1;

  // ---- Weight B-fragments in registers (loaded once).
  // Tiles 0..2: A=u, 16 cols = gates {0,1},{2,3},{4,5} x 8 cols.
  // Tile  3   : A=h, cols 0..7 = gate-5 rows (h@W5), cols 8..15 zero.
  f16x8 bW[16];
  {
    int grow = 0;
    bool valid = true;
    if (wave < 3) {
      int gate = 2 * wave + (n16 >> 3);
      grow = gate * HHH + wg * CC + (n16 & 7);
    } else if (n16 < 8) {
      grow = 5 * HHH + wg * CC + n16;
    } else {
      valid = false;
    }
    const float* wr = W + (size_t)grow * DD;
#pragma unroll
    for (int kk = 0; kk < 16; ++kk) {
      f16x8 v;
      if (valid) {
        const float* p = wr + kk * 32 + q * 8;
#pragma unroll
        for (int j = 0; j < 8; ++j) v[j] = (f16)p[j];
      } else {
#pragma unroll
        for (int j = 0; j < 8; ++j) v[j] = (f16)0.0f;
      }
      bW[kk] = v;
    }
  }

  // ---- Staging indices. Thread's i-th chunk = cols k..k+3 of row m of the
  // flat [16][512] matrix. LDS granule (8 f16): logical (kk*64 + L),
  // physical (kk*64 + (L ^ kk)) — XOR swizzle keeps ds_write at the 4-way
  // floor and ds_read_b128 conflict-free.
  int soffv[8], pidx[8];
  size_t xcm[8];
#pragma unroll
  for (int i = 0; i < 8; ++i) {
    int e = (tid + i * BLK) * 4;
    int m = e >> 9;
    int k = e & 511;
    pidx[i] = m * 256 + (k >> 1);      // u64 pair index (k multiple of 4)
    xcm[i] = (size_t)m * TT * DD + k;  // x[b=m][t][k] base
    int kk = k >> 5, qq = (k >> 3) & 3, j0 = k & 7;
    int L = qq * 16 + m;
    soffv[i] = (kk * 64 + (L ^ kk)) * 8 + j0;
  }

  // ---- Epilogue constants (threads 0..127: b = tid>>3, n = tid&7).
  const int eb = tid >> 3;
  const int en = tid & 7;
  float bb0 = 0, bb1 = 0, bb2 = 0, bb3 = 0, bb4 = 0, bb5 = 0;
  int mylen = 0;
  if (tid < 128) {
    int gc = wg * CC + en;
    bb0 = bias[0 * HHH + gc];
    bb1 = bias[1 * HHH + gc];
    bb2 = bias[2 * HHH + gc];
    bb3 = bias[3 * HHH + gc];
    bb4 = bias[4 * HHH + gc];
    bb5 = bias[5 * HHH + gc];
    mylen = lengths[eb];
    cbuf[tid] = 0.0f;
  }

  // Poll base: this WG's replica only (reader dilution).
  u64* const myrep = hex + (size_t)(wg & repmask) * 8192;

  // Prefetch x(t=0).
  f32x4 xv[8];
#pragma unroll
  for (int i = 0; i < 8; ++i) xv[i] = *(const f32x4*)(x + xcm[i]);

  __syncthreads();

  for (int t = 0; t < TT; ++t) {
    // ---- Poll h(t): tag == t in parity slot t&1 of OUR replica. Every
    // round re-issues ALL 16 loads in parallel (one IC round-trip per
    // round); the successful round IS the data fetch.
    const u64* hb = myrep + (size_t)(t & 1) * 4096;
    const unsigned wtag = (unsigned)t;
    u64 w0[8], w1[8];
    for (;;) {
#pragma unroll
      for (int i = 0; i < 8; ++i) {
        w0[i] = __hip_atomic_load(hb + pidx[i], __ATOMIC_RELAXED,
                                  __HIP_MEMORY_SCOPE_AGENT);
        w1[i] = __hip_atomic_load(hb + pidx[i] + 1, __ATOMIC_RELAXED,
                                  __HIP_MEMORY_SCOPE_AGENT);
      }
      unsigned bad = 0;
#pragma unroll
      for (int i = 0; i < 8; ++i)
        bad |= ((unsigned)(w0[i] >> 32) ^ wtag) |
               ((unsigned)(w1[i] >> 32) ^ wtag);
      if (bad == 0) break;
    }

    // ---- Stage u = f16(x)+h and h into LDS (swizzled).
#pragma unroll
    for (int i = 0; i < 8; ++i) {
      f16x4 hv;
      hv[0] = h_lo(w0[i]);
      hv[1] = h_hi(w0[i]);
      hv[2] = h_lo(w1[i]);
      hv[3] = h_hi(w1[i]);
      f16x4 uv;
#pragma unroll
      for (int j = 0; j < 4; ++j) uv[j] = (f16)xv[i][j] + hv[j];
      *(f16x4*)(u_sw + soffv[i]) = uv;
      *(f16x4*)(h_sw + soffv[i]) = hv;
    }
    __syncthreads();

    // ---- MFMA: wave's 16-col tile, K=512, 4 independent chains.
    f32x4 acc0 = {0.f, 0.f, 0.f, 0.f}, acc1 = {0.f, 0.f, 0.f, 0.f};
    f32x4 acc2 = {0.f, 0.f, 0.f, 0.f}, acc3 = {0.f, 0.f, 0.f, 0.f};
    const f16* asrc = (wave < 3) ? u_sw : h_sw;
#pragma unroll
    for (int kk = 0; kk < 16; kk += 4) {
      f16x8 a0 = *(const f16x8*)(asrc + (kk * 64 + (lane ^ kk)) * 8);
      f16x8 a1 =
          *(const f16x8*)(asrc + ((kk + 1) * 64 + (lane ^ (kk + 1))) * 8);
      f16x8 a2 =
          *(const f16x8*)(asrc + ((kk + 2) * 64 + (lane ^ (kk + 2))) * 8);
      f16x8 a3 =
          *(const f16x8*)(asrc + ((kk + 3) * 64 + (lane ^ (kk + 3))) * 8);
      acc0 = __builtin_amdgcn_mfma_f32_16x16x32_f16(a0, bW[kk], acc0, 0, 0, 0);
      acc1 =
          __builtin_amdgcn_mfma_f32_16x16x32_f16(a1, bW[kk + 1], acc1, 0, 0, 0);
      acc2 =
          __builtin_amdgcn_mfma_f32_16x16x32_f16(a2, bW[kk + 2], acc2, 0, 0, 0);
      acc3 =
          __builtin_amdgcn_mfma_f32_16x16x32_f16(a3, bW[kk + 3], acc3, 0, 0, 0);
    }
#pragma unroll
    for (int r = 0; r < 4; ++r)
      gbuf[wave * 272 + (q * 4 + r) * 17 + n16] =
          (acc0[r] + acc1[r]) + (acc2[r] + acc3[r]);
    __syncthreads();

    // ---- Epilogue (fp32) + replicated publish (waves 0-1; partner via
    // shfl). Each publishing pair stores its tagged u64 to ALL replicas —
    // fire-and-forget; acks drain under the next step's poll.
    if (tid < 128) {
      float g0 = gbuf[0 * 272 + eb * 17 + en] + 2.f * bb0;      // i
      float g1 = gbuf[0 * 272 + eb * 17 + en + 8] + 2.f * bb1;  // f
      float g2 = gbuf[1 * 272 + eb * 17 + en] + 2.f * bb2;      // m~
      float g3 = gbuf[1 * 272 + eb * 17 + en + 8] + 2.f * bb3;  // o
      float g4 = gbuf[2 * 272 + eb * 17 + en] + 2.f * bb4;      // hw
      float p5 = gbuf[2 * 272 + eb * 17 + en + 8];              // (x+h)@W5
      float qv = gbuf[3 * 272 + eb * 17 + en];                  // h@W5
      float ig = sigf(g0), fg = sigf(g1), mt = tanhfast(g2);
      float og = sigf(g3), hwv = sigf(g4);
      float pi5 = p5 - qv + bb5;
      float cold = cbuf[tid];
      float mem = ig * mt + fg * cold;
      float o1 = og * tanhfast(mem);
      float ov = hwv * o1 + (1.0f - hwv) * pi5;
      float msk = (t < mylen) ? 1.0f : 0.0f;
      ov *= msk;
      mem *= msk;
      cbuf[tid] = mem;

      unsigned hbits =
          (unsigned)__builtin_bit_cast(unsigned short, (f16)ov);
      unsigned other = (unsigned)__shfl_xor((int)hbits, 1, 64);
      if ((en & 1) == 0) {
        u64 wv = (u64)(hbits & 0xffffu) | ((u64)(other & 0xffffu) << 16) |
                 ((u64)(unsigned)(t + 1) << 32);
        u64* pdst = hex + (size_t)((t + 1) & 1) * 4096 + eb * 256 + wg * 4 +
                    (en >> 1);
        for (int r = 0; r < nrep; ++r) {
          __hip_atomic_store(pdst, wv, __ATOMIC_RELAXED,
                             __HIP_MEMORY_SCOPE_AGENT);
          pdst += 8192;
        }
      }
      // Out store after publish: keep the publishes at the head of the
      // store queue.
      out[((size_t)eb * TT + t) * HHH + wg * CC + en] = ov;
    }

    // Prefetch x(t+1); latency hides under next step's tag polling.
    if (t + 1 < TT) {
#pragma unroll
      for (int i = 0; i < 8; ++i)
        xv[i] = *(const f32x4*)(x + xcm[i] + (size_t)(t + 1) * DD);
    }
    // No trailing __syncthreads: next-step staging only touches u_sw/h_sw,
    // whose step-t reads all completed before the post-MFMA barrier; gbuf
    // writes for t+1 are fenced by the next post-staging barrier, which
    // cannot be reached before this WG's own publish (poll includes own
    // columns). Replica parity reuse: identical induction — slot p is
    // rewritten at t+2 only after all WGs published t+1, i.e. consumed
    // slot p's tag-t contents.
  }
}

extern "C" void kernel_launch(void* const* d_in, const int* in_sizes, int n_in,
                              void* d_out, int out_size, void* d_ws,
                              size_t ws_size, hipStream_t stream) {
  (void)in_sizes;
  (void)n_in;
  (void)out_size;
  const float* x = (const float*)d_in[0];
  const int* lengths = (const int*)d_in[1];
  const float* W = (const float*)d_in[2];
  const float* bias = (const float*)d_in[3];
  float* out = (float*)d_out;

  // Workspace: [nrep][2][4096] tagged u64. nrep=8 (512KB, available per
  // R7's successful 590KB run) unless the pool is smaller -> exact R3.
  u64* hex = (u64*)d_ws;
  int nrep = (ws_size >= (size_t)8 * 8192 * sizeof(u64)) ? 8 : 1;
  hipMemsetAsync(d_ws, 0, (size_t)nrep * 8192 * sizeof(u64), stream);

  lstm_scan<<<dim3(NG), dim3(BLK), 0, stream>>>(x, lengths, W, bias, out, hex,
                                                nrep - 1);
}